// Round 4
// baseline (312.277 us; speedup 1.0000x reference)
//
#include <hip/hip_runtime.h>
#include <hip/hip_bf16.h>
#include <math.h>

// ViT Vector Quantizer: z [32,1024,32] f32, embedding [8192,32] f32.
// Outputs (concat, read as f32): z_q_out [N*D], loss [1], idx [N] (as floats).
//
// R4 structure:
//   K0 k_norm_emb : normalize codebook -> en, h=0.5*|en|^2; zero loss
//   K1 k_argmin   : codebook rows fetched via wave-uniform s_load_dwordx16
//                   (scalar pipe, zero VALU/LDS cost), manual ping-pong
//                   prefetch distance 1; RPT=2 keeps live state ~80 VGPR
//                   (RPT=4 forced AGPR parking -> phantom VALU in R2/R3).
//                   argmax of s = en.zf - h  (== argmin d, d = zsq - 2s exactly).
//   K2 k_epi      : min-reduce split partials, gather en[idx], write outputs.

#define D 32
#define RPT 2            // rows per thread in k_argmin (keep VGPR < 128!)
#define KCHUNK 256       // codebook rows per K-split
#define EPS 1e-12f

typedef float f16v __attribute__((ext_vector_type(16)));

__global__ __launch_bounds__(256) void k_norm_emb(const float* __restrict__ e,
                                                  float* __restrict__ en,
                                                  float* __restrict__ en_h,
                                                  int K,
                                                  unsigned long long* __restrict__ mp,
                                                  int mp_init_count,
                                                  float* __restrict__ loss) {
  int row = blockIdx.x * 256 + threadIdx.x;
  if (row == 0) *loss = 0.f;
  for (int i = row; i < mp_init_count; i += gridDim.x * 256)
    mp[i] = ~0ull;                      // +inf key (atomic-fallback mode only)
  if (row >= K) return;

  const float4* p = reinterpret_cast<const float4*>(e + (size_t)row * D);
  float v[D];
#pragma unroll
  for (int j = 0; j < D / 4; ++j) {
    float4 q = p[j];
    v[4 * j + 0] = q.x; v[4 * j + 1] = q.y; v[4 * j + 2] = q.z; v[4 * j + 3] = q.w;
  }
  float ss = 0.f;
#pragma unroll
  for (int d = 0; d < D; ++d) ss = fmaf(v[d], v[d], ss);
  float n = fmaxf(sqrtf(ss), EPS);
  float s2 = 0.f;
  float4* o = reinterpret_cast<float4*>(en + (size_t)row * D);
#pragma unroll
  for (int j = 0; j < D / 4; ++j) {
    float4 q;
    q.x = v[4 * j + 0] / n;   // true division mirrors reference x / max(n,eps)
    q.y = v[4 * j + 1] / n;
    q.z = v[4 * j + 2] / n;
    q.w = v[4 * j + 3] / n;
    s2 = fmaf(q.x, q.x, fmaf(q.y, q.y, fmaf(q.z, q.z, fmaf(q.w, q.w, s2))));
    o[j] = q;
  }
  en_h[row] = 0.5f * s2;      // exact halving; d = zsq + 2h - 2(s+h) = zsq - 2s
}

// One (row0,row1) distance pair against codebook row held in scalar regs.
#define COMPUTE(CA0, CA1, H, KIDX)                                      \
  {                                                                     \
    float a0 = -(H), a1 = -(H);                                         \
    _Pragma("unroll") for (int j = 0; j < 16; ++j) {                    \
      a0 = fmaf(v0[j], (CA0)[j], a0);                                   \
      a1 = fmaf(v1[j], (CA0)[j], a1);                                   \
    }                                                                   \
    _Pragma("unroll") for (int j = 0; j < 16; ++j) {                    \
      a0 = fmaf(v0[16 + j], (CA1)[j], a0);                              \
      a1 = fmaf(v1[16 + j], (CA1)[j], a1);                              \
    }                                                                   \
    bool c0 = a0 > sm0, c1 = a1 > sm1;   /* strict > -> first max kept */\
    sm0 = c0 ? a0 : sm0; kb0 = c0 ? (KIDX) : kb0;                       \
    sm1 = c1 ? a1 : sm1; kb1 = c1 ? (KIDX) : kb1;                       \
  }

template <int MODE>
__global__ __launch_bounds__(256, 4) void k_argmin(const float* __restrict__ z,
                                                   const float* __restrict__ en,
                                                   const float* __restrict__ en_h,
                                                   unsigned long long* __restrict__ mp,
                                                   int N) {
  const int t = threadIdx.x;
  const int rowbase = blockIdx.x * (256 * RPT);
  const int k0 = blockIdx.y * KCHUNK;

  // --- load + normalize 2 z rows (coalesced float4) ---
  float v0[D], v1[D];
  {
    const float4* p0 = reinterpret_cast<const float4*>(z + (size_t)(rowbase + t) * D);
    const float4* p1 = reinterpret_cast<const float4*>(z + (size_t)(rowbase + 256 + t) * D);
#pragma unroll
    for (int j = 0; j < D / 4; ++j) {
      float4 q0 = p0[j], q1 = p1[j];
      v0[4 * j + 0] = q0.x; v0[4 * j + 1] = q0.y; v0[4 * j + 2] = q0.z; v0[4 * j + 3] = q0.w;
      v1[4 * j + 0] = q1.x; v1[4 * j + 1] = q1.y; v1[4 * j + 2] = q1.z; v1[4 * j + 3] = q1.w;
    }
    float s0 = 0.f, s1 = 0.f;
#pragma unroll
    for (int d = 0; d < D; ++d) { s0 = fmaf(v0[d], v0[d], s0); s1 = fmaf(v1[d], v1[d], s1); }
    float n0 = fmaxf(sqrtf(s0), EPS), n1 = fmaxf(sqrtf(s1), EPS);
#pragma unroll
    for (int d = 0; d < D; ++d) { v0[d] = v0[d] / n0; v1[d] = v1[d] / n1; }
  }

  // --- codebook stream: wave-uniform 64B scalar loads, ping-pong prefetch ---
  const f16v* eb = reinterpret_cast<const f16v*>(en + (size_t)k0 * D);  // 2 per row
  const float* hb = en_h + k0;

  float sm0 = -3.4e38f, sm1 = -3.4e38f;
  int kb0 = k0, kb1 = k0;

  f16v ca0 = eb[0], ca1 = eb[1];
  float ha = hb[0];

  for (int kk = 0; kk < KCHUNK; kk += 2) {
    // prefetch row kk+1 while computing kk
    f16v cb0 = eb[2 * kk + 2], cb1 = eb[2 * kk + 3];
    float hbv = hb[kk + 1];
    COMPUTE(ca0, ca1, ha, k0 + kk);
    // prefetch row kk+2 (one-row overread on last iter lands in en_h/mp: safe)
    ca0 = eb[2 * kk + 4]; ca1 = eb[2 * kk + 5];
    ha = hb[kk + 2];
    COMPUTE(cb0, cb1, hbv, k0 + kk + 1);
  }

  // --- pack (monotone-decreasing-in-s key | k); min-merge == first-min of d ---
  unsigned o0 = __float_as_uint(sm0);
  o0 = (o0 & 0x80000000u) ? ~o0 : (o0 | 0x80000000u);
  unsigned o1 = __float_as_uint(sm1);
  o1 = (o1 & 0x80000000u) ? ~o1 : (o1 | 0x80000000u);
  unsigned long long p0 = ((unsigned long long)(~o0) << 32) | (unsigned)kb0;
  unsigned long long p1 = ((unsigned long long)(~o1) << 32) | (unsigned)kb1;
  if (MODE == 0) {
    mp[(size_t)blockIdx.y * N + rowbase + t] = p0;          // coalesced stores
    mp[(size_t)blockIdx.y * N + rowbase + 256 + t] = p1;
  } else {
    atomicMin(&mp[rowbase + t], p0);
    atomicMin(&mp[rowbase + 256 + t], p1);
  }
}

__global__ __launch_bounds__(256) void k_epi(const float* __restrict__ z,
                                             const float* __restrict__ en,
                                             const unsigned long long* __restrict__ mp,
                                             int nsplit, int N,
                                             float* __restrict__ out_z,
                                             float* __restrict__ loss,
                                             float* __restrict__ out_idx,
                                             float scale) {
  int row = blockIdx.x * 256 + threadIdx.x;
  unsigned long long m = mp[row];
  for (int s = 1; s < nsplit; ++s) {
    unsigned long long m2 = mp[(size_t)s * N + row];
    m = (m2 < m) ? m2 : m;   // min key -> max s -> min d; tie -> min k
  }
  int kb = (int)(unsigned)(m & 0xFFFFFFFFull);
  out_idx[row] = (float)kb;  // whole out buffer read back as f32

  const float4* p = reinterpret_cast<const float4*>(z + (size_t)row * D);
  float4 q[D / 4];
#pragma unroll
  for (int j = 0; j < D / 4; ++j) q[j] = p[j];
  float ss = 0.f;
#pragma unroll
  for (int j = 0; j < D / 4; ++j)
    ss = fmaf(q[j].x, q[j].x, fmaf(q[j].y, q[j].y, fmaf(q[j].z, q[j].z, fmaf(q[j].w, q[j].w, ss))));
  float n = fmaxf(sqrtf(ss), EPS);

  const float4* ep = reinterpret_cast<const float4*>(en + (size_t)kb * D);
  float4* op = reinterpret_cast<float4*>(out_z + (size_t)row * D);
  float s = 0.f;
#pragma unroll
  for (int j = 0; j < D / 4; ++j) {
    float4 e = ep[j];
    float4 o;
    o.x = q[j].x + (e.x - q[j].x);  // STE forward value, reference op order
    o.y = q[j].y + (e.y - q[j].y);
    o.z = q[j].z + (e.z - q[j].z);
    o.w = q[j].w + (e.w - q[j].w);
    op[j] = o;
    float dx = e.x - q[j].x / n;  float dy = e.y - q[j].y / n;
    float dz = e.z - q[j].z / n;  float dw = e.w - q[j].w / n;
    s = fmaf(dx, dx, fmaf(dy, dy, fmaf(dz, dz, fmaf(dw, dw, s))));
  }

#pragma unroll
  for (int off = 32; off > 0; off >>= 1) s += __shfl_down(s, off, 64);
  __shared__ float wsum[4];
  int lane = threadIdx.x & 63, wid = threadIdx.x >> 6;
  if (lane == 0) wsum[wid] = s;
  __syncthreads();
  if (threadIdx.x == 0) {
    float tt = (wsum[0] + wsum[1]) + (wsum[2] + wsum[3]);
    atomicAdd(loss, tt * scale);
  }
}

extern "C" void kernel_launch(void* const* d_in, const int* in_sizes, int n_in,
                              void* d_out, int out_size, void* d_ws, size_t ws_size,
                              hipStream_t stream) {
  const float* z = (const float*)d_in[0];
  const float* emb = (const float*)d_in[1];
  const int N = in_sizes[0] / D;  // 32768
  const int K = in_sizes[1] / D;  // 8192

  float* out = (float*)d_out;
  float* out_z = out;                        // N*D
  float* loss = out + (size_t)N * D;         // 1
  float* out_idx = out + (size_t)N * D + 1;  // N

  float* en = (float*)d_ws;                  // K*D f32   (1 MB)
  float* en_h = en + (size_t)K * D;          // K f32     (32 KB)
  unsigned long long* mp =
      (unsigned long long*)(en_h + K);       // partials (8B-aligned offset)

  const int KSPLIT = K / KCHUNK;             // 32
  size_t need = (size_t)K * D * 4 + (size_t)K * 4 + (size_t)KSPLIT * N * 8;
  int mode = (ws_size != 0 && ws_size < need) ? 1 : 0;  // 1 = atomic fallback

  k_norm_emb<<<dim3((K + 255) / 256), 256, 0, stream>>>(
      emb, en, en_h, K, mp, mode ? N : 0, loss);

  if (mode == 0) {
    k_argmin<0><<<dim3(N / (256 * RPT), KSPLIT), 256, 0, stream>>>(z, en, en_h, mp, N);
    k_epi<<<dim3(N / 256), 256, 0, stream>>>(
        z, en, mp, KSPLIT, N, out_z, loss, out_idx, 1.25f / (float)((size_t)N * D));
  } else {
    k_argmin<1><<<dim3(N / (256 * RPT), KSPLIT), 256, 0, stream>>>(z, en, en_h, mp, N);
    k_epi<<<dim3(N / 256), 256, 0, stream>>>(
        z, en, mp, 1, N, out_z, loss, out_idx, 1.25f / (float)((size_t)N * D));
  }
}